// Round 1
// baseline (429.919 us; speedup 1.0000x reference)
//
#include <hip/hip_runtime.h>

// Problem constants (from reference)
//   V_SIZE    = [0.1, 0.1, 0.2]
//   PC_MIN    = [0.0, -40.0, -3.0]
//   NORMALIZER= [0.1, 0.1, 0.2, 0.06]
//   BN_EPS    = 1e-5
// C = 64 channels, NS = 16 samples/point.

#define CH 64

// ---------------------------------------------------------------------------
// Kernel 1: per-voxel MLP  Hv[m][o] = relu((dot(v_features[m,:], W[o,:]) - mean[o])*g/sqrt(var+eps) + beta[o])
// Block: 256 threads, 16 voxel rows per block.
// Thread t: o = t&63 (output channel), rq = t>>6 -> rows rq*4 .. rq*4+3.
// W staged in LDS with stride 65 (bank = o%32 across lanes -> 2-way, free).
// ---------------------------------------------------------------------------
__global__ __launch_bounds__(256) void voxel_mlp_kernel(
    const float* __restrict__ v_features,   // [M][64]
    const float* __restrict__ W,            // [64][64] row-major W[o][c]
    const float* __restrict__ gamma,
    const float* __restrict__ beta,
    const float* __restrict__ bn_mean,
    const float* __restrict__ bn_var,
    float* __restrict__ Hv,                 // [M][64] out
    int M)
{
    __shared__ float Wl[64 * 65];
    __shared__ float rows[16 * 64];

    const int t = threadIdx.x;
    const int base = blockIdx.x * 16;

    // Stage W: global coalesced read, LDS write Wl[o*65 + c] (lanes -> consecutive c, conflict-free)
    #pragma unroll
    for (int i = 0; i < 16; ++i) {
        int e = t + i * 256;          // 0..4095
        int o = e >> 6, c = e & 63;
        Wl[o * 65 + c] = W[e];
    }
    // Stage 16 voxel rows
    #pragma unroll
    for (int i = 0; i < 4; ++i) {
        int e = t + i * 256;          // 0..1023
        int r = e >> 6, c = e & 63;
        int gr = base + r;
        rows[e] = (gr < M) ? v_features[gr * CH + c] : 0.0f;
    }
    __syncthreads();

    const int o  = t & 63;
    const int rq = t >> 6;

    float acc0 = 0.f, acc1 = 0.f, acc2 = 0.f, acc3 = 0.f;
    const float* r0 = &rows[(rq * 4 + 0) * CH];
    const float* r1 = &rows[(rq * 4 + 1) * CH];
    const float* r2 = &rows[(rq * 4 + 2) * CH];
    const float* r3 = &rows[(rq * 4 + 3) * CH];
    const float* wp = &Wl[o * 65];

    #pragma unroll
    for (int c = 0; c < CH; ++c) {
        float w = wp[c];              // bank o%32: 2-way across 64 lanes = free
        acc0 += w * r0[c];            // broadcast reads
        acc1 += w * r1[c];
        acc2 += w * r2[c];
        acc3 += w * r3[c];
    }

    const float scale = gamma[o] * rsqrtf(bn_var[o] + 1e-5f);
    const float shift = beta[o] - bn_mean[o] * scale;

    float h0 = fmaxf(acc0 * scale + shift, 0.f);
    float h1 = fmaxf(acc1 * scale + shift, 0.f);
    float h2 = fmaxf(acc2 * scale + shift, 0.f);
    float h3 = fmaxf(acc3 * scale + shift, 0.f);

    int gr = base + rq * 4;
    if (gr + 0 < M) Hv[(gr + 0) * CH + o] = h0;
    if (gr + 1 < M) Hv[(gr + 1) * CH + o] = h1;
    if (gr + 2 < M) Hv[(gr + 2) * CH + o] = h2;
    if (gr + 3 < M) Hv[(gr + 3) * CH + o] = h3;
}

// ---------------------------------------------------------------------------
// Kernel 2: geo-weighted masked-mean pooling.
// One wave (64 lanes) per point n; lane = output channel o.
// out[n][o] = p_features[n][o] + (1/denom) * sum_s mask * Hv[m_s][o] * geo_s[o&3]
// ---------------------------------------------------------------------------
__global__ __launch_bounds__(256) void pool_kernel(
    const int*   __restrict__ v_indices,   // [M][4]
    const float* __restrict__ p_coords,    // [N][4]
    const float* __restrict__ p_features,  // [N][64]
    const int*   __restrict__ p_map,       // [N][NS]
    const float* __restrict__ p_mask,      // [N][NS]
    const float* __restrict__ Hv,          // [M][64]
    float* __restrict__ out,               // [N][64]
    int N, int NS)
{
    const int wave = threadIdx.x >> 6;
    const int lane = threadIdx.x & 63;
    const int n = blockIdx.x * 4 + wave;
    if (n >= N) return;

    // centers (wave-uniform broadcast load)
    const float cx = p_coords[n * 4 + 1];
    const float cy = p_coords[n * 4 + 2];
    const float cz = p_coords[n * 4 + 3];

    const int q = lane & 3;

    float acc = 0.f;
    float denom = 0.f;

    #pragma unroll 4
    for (int s = 0; s < NS; ++s) {
        const float msk = p_mask[n * NS + s];   // uniform across wave
        denom += msk;
        if (msk != 0.f) {                        // wave-uniform branch
            const int m = p_map[n * NS + s];
            const int4 vi = *reinterpret_cast<const int4*>(&v_indices[m * 4]);
            // v_xyz = (idx[[3,2,1]] + 0.5) * V_SIZE + PC_MIN
            const float rx = (((float)vi.w + 0.5f) * 0.1f + 0.0f)  - cx;
            const float ry = (((float)vi.z + 0.5f) * 0.1f - 40.0f) - cy;
            const float rz = (((float)vi.y + 0.5f) * 0.2f - 3.0f)  - cz;
            const float d  = rx * rx + ry * ry + rz * rz;
            // geo = [rx,ry,rz,d] / NORMALIZER, replicated every 4 channels
            const float g0 = rx / 0.1f;
            const float g1 = ry / 0.1f;
            const float g2 = rz / 0.2f;
            const float g3 = d  / 0.060000000000000005f;
            const float g  = (q & 2) ? ((q & 1) ? g3 : g2)
                                     : ((q & 1) ? g1 : g0);
            const float h = Hv[m * CH + lane];   // coalesced 256B gather
            acc += h * g * msk;
        }
    }

    denom = fmaxf(denom, 1.0f);
    out[n * CH + lane] = p_features[n * CH + lane] + acc / denom;
}

extern "C" void kernel_launch(void* const* d_in, const int* in_sizes, int n_in,
                              void* d_out, int out_size, void* d_ws, size_t ws_size,
                              hipStream_t stream) {
    const int*   v_indices  = (const int*)  d_in[0];
    const float* v_features = (const float*)d_in[1];
    const float* p_coords   = (const float*)d_in[2];
    const float* p_features = (const float*)d_in[3];
    const int*   p_map      = (const int*)  d_in[4];
    const float* p_mask     = (const float*)d_in[5];
    const float* W          = (const float*)d_in[6];
    const float* gamma      = (const float*)d_in[7];
    const float* beta       = (const float*)d_in[8];
    const float* bn_mean    = (const float*)d_in[9];
    const float* bn_var     = (const float*)d_in[10];

    const int M  = in_sizes[1] / CH;
    const int N  = in_sizes[3] / CH;
    const int NS = in_sizes[4] / N;

    float* Hv = (float*)d_ws;   // M*64 floats

    {
        dim3 grid((M + 15) / 16);
        voxel_mlp_kernel<<<grid, 256, 0, stream>>>(v_features, W, gamma, beta,
                                                   bn_mean, bn_var, Hv, M);
    }
    {
        dim3 grid((N + 3) / 4);
        pool_kernel<<<grid, 256, 0, stream>>>(v_indices, p_coords, p_features,
                                              p_map, p_mask, Hv,
                                              (float*)d_out, N, NS);
    }
}

// Round 2
// 168.561 us; speedup vs baseline: 2.5505x; 2.5505x over previous
//
#include <hip/hip_runtime.h>
#include <hip/hip_fp16.h>

#define CH 64

// ---------------------------------------------------------------------------
// Kernel 1: per-voxel MLP  Hv[m][o] = relu(BN(dot(v_features[m,:], W[o,:])))
// stored as fp16, plus per-voxel xyz (float4).
// Block: 256 threads, 16 voxel rows. W in LDS stride-68 floats (16B aligned,
// b128 reads spread evenly over banks). Row reads are wave-uniform broadcasts.
// ---------------------------------------------------------------------------
__global__ __launch_bounds__(256) void voxel_mlp_kernel(
    const int*   __restrict__ v_indices,    // [M][4]
    const float* __restrict__ v_features,   // [M][64]
    const float* __restrict__ W,            // [64][64]
    const float* __restrict__ gamma,
    const float* __restrict__ beta,
    const float* __restrict__ bn_mean,
    const float* __restrict__ bn_var,
    _Float16* __restrict__ Hvh,             // [M][64] out (fp16)
    float4*   __restrict__ Vxyz,            // [M] out (x,y,z,0)
    int M)
{
    __shared__ float Wl[64 * 68];
    __shared__ float rowsf[16 * 64];

    const int t = threadIdx.x;
    const int base = blockIdx.x * 16;

    #pragma unroll
    for (int i = 0; i < 16; ++i) {
        int e = t + i * 256;                 // 0..4095
        Wl[(e >> 6) * 68 + (e & 63)] = W[e];
    }
    #pragma unroll
    for (int i = 0; i < 4; ++i) {
        int e = t + i * 256;                 // 0..1023
        int gr = base + (e >> 6);
        rowsf[e] = (gr < M) ? v_features[gr * CH + (e & 63)] : 0.0f;
    }
    if (t < 16 && base + t < M) {
        int4 vi = ((const int4*)v_indices)[base + t];
        float4 vx;
        vx.x = ((float)vi.w + 0.5f) * 0.1f + 0.0f;
        vx.y = ((float)vi.z + 0.5f) * 0.1f - 40.0f;
        vx.z = ((float)vi.y + 0.5f) * 0.2f - 3.0f;
        vx.w = 0.0f;
        Vxyz[base + t] = vx;
    }
    __syncthreads();

    const int o  = t & 63;
    const int rq = t >> 6;

    const float4* wp = (const float4*)&Wl[o * 68];
    const float4* r0 = (const float4*)&rowsf[(rq * 4 + 0) * CH];
    const float4* r1 = (const float4*)&rowsf[(rq * 4 + 1) * CH];
    const float4* r2 = (const float4*)&rowsf[(rq * 4 + 2) * CH];
    const float4* r3 = (const float4*)&rowsf[(rq * 4 + 3) * CH];

    float acc0 = 0.f, acc1 = 0.f, acc2 = 0.f, acc3 = 0.f;
    #pragma unroll
    for (int c = 0; c < 16; ++c) {
        float4 w = wp[c];
        float4 a;
        a = r0[c];
        acc0 = fmaf(w.x, a.x, acc0); acc0 = fmaf(w.y, a.y, acc0);
        acc0 = fmaf(w.z, a.z, acc0); acc0 = fmaf(w.w, a.w, acc0);
        a = r1[c];
        acc1 = fmaf(w.x, a.x, acc1); acc1 = fmaf(w.y, a.y, acc1);
        acc1 = fmaf(w.z, a.z, acc1); acc1 = fmaf(w.w, a.w, acc1);
        a = r2[c];
        acc2 = fmaf(w.x, a.x, acc2); acc2 = fmaf(w.y, a.y, acc2);
        acc2 = fmaf(w.z, a.z, acc2); acc2 = fmaf(w.w, a.w, acc2);
        a = r3[c];
        acc3 = fmaf(w.x, a.x, acc3); acc3 = fmaf(w.y, a.y, acc3);
        acc3 = fmaf(w.z, a.z, acc3); acc3 = fmaf(w.w, a.w, acc3);
    }

    const float scale = gamma[o] * rsqrtf(bn_var[o] + 1e-5f);
    const float shift = beta[o] - bn_mean[o] * scale;

    float h0 = fmaxf(fmaf(acc0, scale, shift), 0.f);
    float h1 = fmaxf(fmaf(acc1, scale, shift), 0.f);
    float h2 = fmaxf(fmaf(acc2, scale, shift), 0.f);
    float h3 = fmaxf(fmaf(acc3, scale, shift), 0.f);

    int gr = base + rq * 4;
    if (gr + 0 < M) Hvh[(gr + 0) * CH + o] = (_Float16)h0;
    if (gr + 1 < M) Hvh[(gr + 1) * CH + o] = (_Float16)h1;
    if (gr + 2 < M) Hvh[(gr + 2) * CH + o] = (_Float16)h2;
    if (gr + 3 < M) Hvh[(gr + 3) * CH + o] = (_Float16)h3;
}

// ---------------------------------------------------------------------------
// Kernel 2: geo-weighted masked-mean pooling.
// One wave per point; lane = channel. Point metadata scalarized via
// readfirstlane -> s_load; all 16 Hv gathers issued up front (16-deep MLP).
// ---------------------------------------------------------------------------
__global__ __launch_bounds__(256) void pool_kernel(
    const float* __restrict__ p_coords,     // [N][4]
    const float* __restrict__ p_features,   // [N][64]
    const int*   __restrict__ p_map,        // [N][16]
    const float* __restrict__ p_mask,       // [N][16]
    const _Float16* __restrict__ Hvh,       // [M][64]
    const float4*   __restrict__ Vxyz,      // [M]
    float* __restrict__ out,                // [N][64]
    int N)
{
    const int lane = threadIdx.x & 63;
    int n = (int)(blockIdx.x * 4) + (threadIdx.x >> 6);
    n = __builtin_amdgcn_readfirstlane(n);
    if (n >= N) return;

    // wave-uniform metadata -> scalar loads
    int   mi[16];
    float mk[16];
    {
        const int4*   pm = (const int4*)(p_map + n * 16);
        const float4* pk = (const float4*)(p_mask + n * 16);
        #pragma unroll
        for (int i = 0; i < 4; ++i) {
            int4 a = pm[i];
            mi[i*4+0] = a.x; mi[i*4+1] = a.y; mi[i*4+2] = a.z; mi[i*4+3] = a.w;
            float4 b = pk[i];
            mk[i*4+0] = b.x; mk[i*4+1] = b.y; mk[i*4+2] = b.z; mk[i*4+3] = b.w;
        }
    }

    // issue all 16 channel gathers (saddr + lane offset), fp16
    float h[16];
    #pragma unroll
    for (int s = 0; s < 16; ++s)
        h[s] = (float)Hvh[mi[s] * CH + lane];

    const float cx = p_coords[n * 4 + 1];
    const float cy = p_coords[n * 4 + 2];
    const float cz = p_coords[n * 4 + 3];
    const int q = lane & 3;

    float acc = 0.f, den = 0.f;
    #pragma unroll
    for (int s = 0; s < 16; ++s) {
        float4 v = Vxyz[mi[s]];              // uniform -> s_load_dwordx4
        float rx = v.x - cx, ry = v.y - cy, rz = v.z - cz;
        float d  = fmaf(rx, rx, fmaf(ry, ry, rz * rz));
        float gl = (q & 1) ? ry * 10.0f : rx * 10.0f;   // 1/0.1f == 10.0f exactly
        float gh = (q & 1) ? d * (1.0f / 0.060000006f)  // 1/NORMALIZER[3]
                           : rz * 5.0f;                  // 1/0.2f == 5.0f exactly
        float g  = (q & 2) ? gh : gl;
        acc = fmaf(h[s] * mk[s], g, acc);
        den += mk[s];
    }

    den = fmaxf(den, 1.0f);
    out[n * CH + lane] = p_features[n * CH + lane] + acc / den;
}

extern "C" void kernel_launch(void* const* d_in, const int* in_sizes, int n_in,
                              void* d_out, int out_size, void* d_ws, size_t ws_size,
                              hipStream_t stream) {
    const int*   v_indices  = (const int*)  d_in[0];
    const float* v_features = (const float*)d_in[1];
    const float* p_coords   = (const float*)d_in[2];
    const float* p_features = (const float*)d_in[3];
    const int*   p_map      = (const int*)  d_in[4];
    const float* p_mask     = (const float*)d_in[5];
    const float* W          = (const float*)d_in[6];
    const float* gamma      = (const float*)d_in[7];
    const float* beta       = (const float*)d_in[8];
    const float* bn_mean    = (const float*)d_in[9];
    const float* bn_var     = (const float*)d_in[10];

    const int M = in_sizes[1] / CH;
    const int N = in_sizes[3] / CH;

    _Float16* Hvh  = (_Float16*)d_ws;                       // M*64 fp16 = M*128 B
    float4*   Vxyz = (float4*)((char*)d_ws + (size_t)M * CH * sizeof(_Float16));

    {
        dim3 grid((M + 15) / 16);
        voxel_mlp_kernel<<<grid, 256, 0, stream>>>(v_indices, v_features, W,
                                                   gamma, beta, bn_mean, bn_var,
                                                   Hvh, Vxyz, M);
    }
    {
        dim3 grid((N + 3) / 4);
        pool_kernel<<<grid, 256, 0, stream>>>(p_coords, p_features, p_map,
                                              p_mask, Hvh, Vxyz,
                                              (float*)d_out, N);
    }
}

// Round 3
// 99.959 us; speedup vs baseline: 4.3010x; 1.6863x over previous
//
#include <hip/hip_runtime.h>

#define CH 64

typedef _Float16 half8  __attribute__((ext_vector_type(8)));
typedef _Float16 half2v __attribute__((ext_vector_type(2)));
typedef float    f32x4  __attribute__((ext_vector_type(4)));

__device__ __forceinline__ half8 cvt_half8(float4 a, float4 b) {
    half8 h;
    h[0] = (_Float16)a.x; h[1] = (_Float16)a.y; h[2] = (_Float16)a.z; h[3] = (_Float16)a.w;
    h[4] = (_Float16)b.x; h[5] = (_Float16)b.y; h[6] = (_Float16)b.z; h[7] = (_Float16)b.w;
    return h;
}

// ---------------------------------------------------------------------------
// Kernel 1: voxel MLP via MFMA fp16 (f32 accumulate), no LDS.
// Block 256 = 4 waves; 64 voxel rows/block (16 per wave).
// Per wave: D[16 rows][64 outs] = A(16x64) * B(64x64), B[c][o] = W[o][c].
// mfma_f32_16x16x32_f16 fragment mapping (lane in [0,64)):
//   A: row = lane&15, k = (lane>>4)*8 + j   (8 f16 / lane)
//   B: col = lane&15, k = (lane>>4)*8 + j
//   D: col = lane&15, row = (lane>>4)*4 + reg
// Output: Hvp[m][32] dwords, dword c = (fp16 h[c], fp16 h[c+32]).
// Also emits Vxyz[m] (float4).
// ---------------------------------------------------------------------------
__global__ __launch_bounds__(256) void voxel_mlp_mfma(
    const int4*   __restrict__ vi4,      // v_indices [M]
    const float4* __restrict__ vf4,      // v_features [M*16]
    const float4* __restrict__ Wf4,      // W [64*16]
    const float*  __restrict__ gamma,
    const float*  __restrict__ beta,
    const float*  __restrict__ bn_mean,
    const float*  __restrict__ bn_var,
    unsigned*     __restrict__ Hvp,      // [M*32] packed half2
    float4*       __restrict__ Vxyz,     // [M]
    int M)
{
    const int t     = threadIdx.x;
    const int lane  = t & 63;
    const int wv    = t >> 6;
    const int row16 = lane & 15;
    const int kgrp  = lane >> 4;
    const int blockRow = blockIdx.x * 64;

    // side-product: per-voxel xyz (first 64 threads)
    if (t < 64) {
        int r = blockRow + t;
        if (r < M) {
            int4 vi = vi4[r];
            float4 vx;
            vx.x = ((float)vi.w + 0.5f) * 0.1f;
            vx.y = ((float)vi.z + 0.5f) * 0.1f - 40.0f;
            vx.z = ((float)vi.y + 0.5f) * 0.2f - 3.0f;
            vx.w = 0.0f;
            Vxyz[r] = vx;
        }
    }

    // B fragments: W[o][c], o = ot*16+row16, c = ck*32 + kgrp*8 + j
    half8 bfrag[4][2];
    #pragma unroll
    for (int ot = 0; ot < 4; ++ot) {
        int o = ot * 16 + row16;
        #pragma unroll
        for (int ck = 0; ck < 2; ++ck) {
            int c4 = ck * 8 + kgrp * 2;
            bfrag[ot][ck] = cvt_half8(Wf4[o * 16 + c4], Wf4[o * 16 + c4 + 1]);
        }
    }

    // A fragments: v_features rows of this wave's tile
    const int rbase = blockRow + wv * 16;
    int rc = rbase + row16; if (rc > M - 1) rc = M - 1;
    half8 afrag[2];
    #pragma unroll
    for (int ck = 0; ck < 2; ++ck) {
        int c4 = ck * 8 + kgrp * 2;
        afrag[ck] = cvt_half8(vf4[rc * 16 + c4], vf4[rc * 16 + c4 + 1]);
    }

    f32x4 acc[4] = {{0.f,0.f,0.f,0.f},{0.f,0.f,0.f,0.f},{0.f,0.f,0.f,0.f},{0.f,0.f,0.f,0.f}};
    #pragma unroll
    for (int ot = 0; ot < 4; ++ot) {
        acc[ot] = __builtin_amdgcn_mfma_f32_16x16x32_f16(afrag[0], bfrag[ot][0], acc[ot], 0, 0, 0);
        acc[ot] = __builtin_amdgcn_mfma_f32_16x16x32_f16(afrag[1], bfrag[ot][1], acc[ot], 0, 0, 0);
    }

    // BN scale/shift for this lane's 4 output channels
    float sc[4], sh[4];
    #pragma unroll
    for (int ot = 0; ot < 4; ++ot) {
        int o = ot * 16 + row16;
        float s = gamma[o] * rsqrtf(bn_var[o] + 1e-5f);
        sc[ot] = s;
        sh[ot] = beta[o] - bn_mean[o] * s;
    }

    // epilogue: relu + pack (c, c+32) -> dword store
    #pragma unroll
    for (int reg = 0; reg < 4; ++reg) {
        int row = rbase + kgrp * 4 + reg;
        if (row < M) {
            #pragma unroll
            for (int ot = 0; ot < 2; ++ot) {
                float v0 = fmaxf(fmaf(acc[ot][reg],     sc[ot],     sh[ot]),     0.f);
                float v1 = fmaxf(fmaf(acc[ot + 2][reg], sc[ot + 2], sh[ot + 2]), 0.f);
                half2v p; p[0] = (_Float16)v0; p[1] = (_Float16)v1;
                *reinterpret_cast<half2v*>(&Hvp[row * 32 + ot * 16 + row16]) = p;
            }
        }
    }
}

// ---------------------------------------------------------------------------
// Kernel 2: pooling. One wave per point, lane = channel.
// Pre-pass: lanes 0-15 compute per-sample weights w[s][q] = mask*geo[q] in
// parallel -> per-wave LDS table; den via 4x shfl_xor.
// Inner loop per sample: v_add + global_load_ushort + cvt + ds_read + fmac.
// ---------------------------------------------------------------------------
__global__ __launch_bounds__(256) void pool_kernel(
    const float*  __restrict__ p_coords,   // [N][4]
    const float*  __restrict__ p_features, // [N][64]
    const int*    __restrict__ p_map,      // [N][16]
    const float*  __restrict__ p_mask,     // [N][16]
    const char*   __restrict__ Hvp,        // [M*128 bytes] packed half2
    const float4* __restrict__ Vxyz,       // [M]
    float* __restrict__ out,               // [N][64]
    int N)
{
    __shared__ float gw[4][16][4];         // [wave][sample][q]
    const int lane = threadIdx.x & 63;
    const int wv   = threadIdx.x >> 6;
    int n = __builtin_amdgcn_readfirstlane((int)blockIdx.x * 4 + wv);
    if (n >= N) return;

    // independent: issue early
    float pf = p_features[n * CH + lane];

    // pre-pass: lane (s = lane&15) computes sample s's weights
    const int s15 = lane & 15;
    int   mi_v = p_map [n * 16 + s15];
    float mk_v = p_mask[n * 16 + s15];
    float4 v = Vxyz[mi_v];
    const float cx = p_coords[n * 4 + 1];
    const float cy = p_coords[n * 4 + 2];
    const float cz = p_coords[n * 4 + 3];
    float rx = v.x - cx, ry = v.y - cy, rz = v.z - cz;
    float d  = fmaf(rx, rx, fmaf(ry, ry, rz * rz));
    float4 w4;
    w4.x = rx * 10.0f * mk_v;
    w4.y = ry * 10.0f * mk_v;
    w4.z = rz * 5.0f  * mk_v;
    w4.w = d * (1.0f / 0.060000006f) * mk_v;
    if (lane < 16)
        *reinterpret_cast<float4*>(&gw[wv][s15][0]) = w4;

    // denom: sum of 16 masks (lanes 16-63 hold replicas of the same values)
    float den = mk_v;
    den += __shfl_xor(den, 1);
    den += __shfl_xor(den, 2);
    den += __shfl_xor(den, 4);
    den += __shfl_xor(den, 8);
    den = fmaxf(den, 1.0f);

    const int q = lane & 3;
    // byte offset of channel `lane` inside a packed 128B Hvp row
    const unsigned loff = (unsigned)((lane & 31) * 4 + (lane >> 5) * 2);
    const int* __restrict__ pmS = p_map + n * 16;   // uniform -> s_load

    float acc = 0.f;
    #pragma unroll
    for (int s = 0; s < 16; ++s) {
        unsigned off = (unsigned)pmS[s] * 128u + loff;   // s_lshl + v_add
        float h = (float)*reinterpret_cast<const _Float16*>(Hvp + off);
        acc = fmaf(h, gw[wv][s][q], acc);
    }

    out[n * CH + lane] = pf + acc / den;
}

extern "C" void kernel_launch(void* const* d_in, const int* in_sizes, int n_in,
                              void* d_out, int out_size, void* d_ws, size_t ws_size,
                              hipStream_t stream) {
    const int*   v_indices  = (const int*)  d_in[0];
    const float* v_features = (const float*)d_in[1];
    const float* p_coords   = (const float*)d_in[2];
    const float* p_features = (const float*)d_in[3];
    const int*   p_map      = (const int*)  d_in[4];
    const float* p_mask     = (const float*)d_in[5];
    const float* W          = (const float*)d_in[6];
    const float* gamma      = (const float*)d_in[7];
    const float* beta       = (const float*)d_in[8];
    const float* bn_mean    = (const float*)d_in[9];
    const float* bn_var     = (const float*)d_in[10];

    const int M = in_sizes[1] / CH;
    const int N = in_sizes[3] / CH;

    unsigned* Hvp  = (unsigned*)d_ws;                       // M * 128 B
    float4*   Vxyz = (float4*)((char*)d_ws + (size_t)M * 128);

    {
        dim3 grid((M + 63) / 64);
        voxel_mlp_mfma<<<grid, 256, 0, stream>>>(
            (const int4*)v_indices, (const float4*)v_features, (const float4*)W,
            gamma, beta, bn_mean, bn_var, Hvp, Vxyz, M);
    }
    {
        dim3 grid((N + 3) / 4);
        pool_kernel<<<grid, 256, 0, stream>>>(
            p_coords, p_features, p_map, p_mask,
            (const char*)Hvp, (const float4*)Vxyz, (float*)d_out, N);
    }
}

// Round 4
// 77.666 us; speedup vs baseline: 5.5355x; 1.2870x over previous
//
#include <hip/hip_runtime.h>

#define CH 64

typedef _Float16 half8  __attribute__((ext_vector_type(8)));
typedef _Float16 half2v __attribute__((ext_vector_type(2)));
typedef float    f32x4  __attribute__((ext_vector_type(4)));

__device__ __forceinline__ half8 cvt_half8(float4 a, float4 b) {
    half8 h;
    h[0] = (_Float16)a.x; h[1] = (_Float16)a.y; h[2] = (_Float16)a.z; h[3] = (_Float16)a.w;
    h[4] = (_Float16)b.x; h[5] = (_Float16)b.y; h[6] = (_Float16)b.z; h[7] = (_Float16)b.w;
    return h;
}

// ---------------------------------------------------------------------------
// Kernel 1: voxel MLP via MFMA fp16 (f32 accumulate). Unchanged from R3
// (validated). Output row m: 32 dwords, dword j = (h[j], h[j+32]) fp16 pair.
// ---------------------------------------------------------------------------
__global__ __launch_bounds__(256) void voxel_mlp_mfma(
    const int4*   __restrict__ vi4,
    const float4* __restrict__ vf4,
    const float4* __restrict__ Wf4,
    const float*  __restrict__ gamma,
    const float*  __restrict__ beta,
    const float*  __restrict__ bn_mean,
    const float*  __restrict__ bn_var,
    unsigned*     __restrict__ Hvp,
    float4*       __restrict__ Vxyz,
    int M)
{
    const int t     = threadIdx.x;
    const int lane  = t & 63;
    const int wv    = t >> 6;
    const int row16 = lane & 15;
    const int kgrp  = lane >> 4;
    const int blockRow = blockIdx.x * 64;

    if (t < 64) {
        int r = blockRow + t;
        if (r < M) {
            int4 vi = vi4[r];
            float4 vx;
            vx.x = ((float)vi.w + 0.5f) * 0.1f;
            vx.y = ((float)vi.z + 0.5f) * 0.1f - 40.0f;
            vx.z = ((float)vi.y + 0.5f) * 0.2f - 3.0f;
            vx.w = 0.0f;
            Vxyz[r] = vx;
        }
    }

    half8 bfrag[4][2];
    #pragma unroll
    for (int ot = 0; ot < 4; ++ot) {
        int o = ot * 16 + row16;
        #pragma unroll
        for (int ck = 0; ck < 2; ++ck) {
            int c4 = ck * 8 + kgrp * 2;
            bfrag[ot][ck] = cvt_half8(Wf4[o * 16 + c4], Wf4[o * 16 + c4 + 1]);
        }
    }

    const int rbase = blockRow + wv * 16;
    int rc = rbase + row16; if (rc > M - 1) rc = M - 1;
    half8 afrag[2];
    #pragma unroll
    for (int ck = 0; ck < 2; ++ck) {
        int c4 = ck * 8 + kgrp * 2;
        afrag[ck] = cvt_half8(vf4[rc * 16 + c4], vf4[rc * 16 + c4 + 1]);
    }

    f32x4 acc[4] = {{0.f,0.f,0.f,0.f},{0.f,0.f,0.f,0.f},{0.f,0.f,0.f,0.f},{0.f,0.f,0.f,0.f}};
    #pragma unroll
    for (int ot = 0; ot < 4; ++ot) {
        acc[ot] = __builtin_amdgcn_mfma_f32_16x16x32_f16(afrag[0], bfrag[ot][0], acc[ot], 0, 0, 0);
        acc[ot] = __builtin_amdgcn_mfma_f32_16x16x32_f16(afrag[1], bfrag[ot][1], acc[ot], 0, 0, 0);
    }

    float sc[4], sh[4];
    #pragma unroll
    for (int ot = 0; ot < 4; ++ot) {
        int o = ot * 16 + row16;
        float s = gamma[o] * rsqrtf(bn_var[o] + 1e-5f);
        sc[ot] = s;
        sh[ot] = beta[o] - bn_mean[o] * s;
    }

    #pragma unroll
    for (int reg = 0; reg < 4; ++reg) {
        int row = rbase + kgrp * 4 + reg;
        if (row < M) {
            #pragma unroll
            for (int ot = 0; ot < 2; ++ot) {
                float v0 = fmaxf(fmaf(acc[ot][reg],     sc[ot],     sh[ot]),     0.f);
                float v1 = fmaxf(fmaf(acc[ot + 2][reg], sc[ot + 2], sh[ot + 2]), 0.f);
                half2v p; p[0] = (_Float16)v0; p[1] = (_Float16)v1;
                *reinterpret_cast<half2v*>(&Hvp[row * 32 + ot * 16 + row16]) = p;
            }
        }
    }
}

// ---------------------------------------------------------------------------
// Kernel 2: pooling, wide-gather version.
// One wave per point. 16 lanes cover one 128B Hv row via dwordx2 -> one
// wave-instruction gathers 4 sample-rows; 4 gathers total per point.
// Lane (g = lane>>4, k = lane&15) owns channels {2k, 2k+1, 2k+32, 2k+33}
// for samples s = g*4 + i (i=0..3). shfl_xor(16,32) sums the 4 groups.
// ---------------------------------------------------------------------------
__global__ __launch_bounds__(256) void pool_kernel(
    const float*  __restrict__ p_coords,   // [N][4]
    const float*  __restrict__ p_features, // [N][64]
    const int*    __restrict__ p_map,      // [N][16]
    const float*  __restrict__ p_mask,     // [N][16]
    const char*   __restrict__ Hvp,        // [M*128 bytes]
    const float4* __restrict__ Vxyz,       // [M]
    float* __restrict__ out,               // [N][64]
    int N)
{
    __shared__ float gws[4][16][4];        // [wave][sample][q]
    const int lane = threadIdx.x & 63;
    const int wv   = threadIdx.x >> 6;
    int n = __builtin_amdgcn_readfirstlane((int)blockIdx.x * 4 + wv);
    if (n >= N) n = N - 1;

    const int g  = lane >> 4;              // sample group (0..3)
    const int k  = lane & 15;              // channel-pair index
    const int q0 = (lane & 1) * 2;         // q of channel 2k (and 2k+32)

    // row indices for this lane's 4 samples: s = g*4 + i
    const int4 m4 = ((const int4*)(p_map + n * 16))[g];

    // issue 4 dwordx2 gathers (each wave-instruction covers 4 rows)
    const unsigned co = (unsigned)k * 8u;
    uint2 h01[4];
    h01[0] = *(const uint2*)(Hvp + ((unsigned)m4.x * 128u + co));
    h01[1] = *(const uint2*)(Hvp + ((unsigned)m4.y * 128u + co));
    h01[2] = *(const uint2*)(Hvp + ((unsigned)m4.z * 128u + co));
    h01[3] = *(const uint2*)(Hvp + ((unsigned)m4.w * 128u + co));

    // prepass: per-sample weights (sample = k; groups are duplicates)
    int   mi = p_map [n * 16 + k];
    float mk = p_mask[n * 16 + k];
    float4 v = Vxyz[mi];
    const float cx = p_coords[n * 4 + 1];
    const float cy = p_coords[n * 4 + 2];
    const float cz = p_coords[n * 4 + 3];
    float rx = v.x - cx, ry = v.y - cy, rz = v.z - cz;
    float d  = fmaf(rx, rx, fmaf(ry, ry, rz * rz));
    if (lane < 16) {
        float4 w4;
        w4.x = rx * 10.0f * mk;
        w4.y = ry * 10.0f * mk;
        w4.z = rz * 5.0f  * mk;
        w4.w = d * (1.0f / 0.060000006f) * mk;
        *reinterpret_cast<float4*>(&gws[wv][k][0]) = w4;
    }
    float den = mk;
    den += __shfl_xor(den, 1);
    den += __shfl_xor(den, 2);
    den += __shfl_xor(den, 4);
    den += __shfl_xor(den, 8);
    den = fmaxf(den, 1.0f);

    // p_features for the storing half-wave
    float2 pf = make_float2(0.f, 0.f);
    if (g < 2)
        pf = *(const float2*)(p_features + n * 64 + g * 32 + k * 2);

    __syncthreads();

    float acc0 = 0.f, acc1 = 0.f, acc2 = 0.f, acc3 = 0.f;
    #pragma unroll
    for (int i = 0; i < 4; ++i) {
        int s = g * 4 + i;
        float2 w = *(const float2*)&gws[wv][s][q0];   // (w[q0], w[q0+1])
        half2v a = __builtin_bit_cast(half2v, h01[i].x);  // (h[2k],   h[2k+32])
        half2v b = __builtin_bit_cast(half2v, h01[i].y);  // (h[2k+1], h[2k+33])
        acc0 = fmaf((float)a[0], w.x, acc0);   // ch 2k
        acc1 = fmaf((float)b[0], w.y, acc1);   // ch 2k+1
        acc2 = fmaf((float)a[1], w.x, acc2);   // ch 2k+32
        acc3 = fmaf((float)b[1], w.y, acc3);   // ch 2k+33
    }
    acc0 += __shfl_xor(acc0, 16); acc0 += __shfl_xor(acc0, 32);
    acc1 += __shfl_xor(acc1, 16); acc1 += __shfl_xor(acc1, 32);
    acc2 += __shfl_xor(acc2, 16); acc2 += __shfl_xor(acc2, 32);
    acc3 += __shfl_xor(acc3, 16); acc3 += __shfl_xor(acc3, 32);

    if (g < 2) {
        float rden = 1.0f / den;
        float2 o;
        if (g == 0) { o.x = fmaf(acc0, rden, pf.x); o.y = fmaf(acc1, rden, pf.y); }
        else        { o.x = fmaf(acc2, rden, pf.x); o.y = fmaf(acc3, rden, pf.y); }
        *reinterpret_cast<float2*>(out + n * 64 + g * 32 + k * 2) = o;
    }
}

extern "C" void kernel_launch(void* const* d_in, const int* in_sizes, int n_in,
                              void* d_out, int out_size, void* d_ws, size_t ws_size,
                              hipStream_t stream) {
    const int*   v_indices  = (const int*)  d_in[0];
    const float* v_features = (const float*)d_in[1];
    const float* p_coords   = (const float*)d_in[2];
    const float* p_features = (const float*)d_in[3];
    const int*   p_map      = (const int*)  d_in[4];
    const float* p_mask     = (const float*)d_in[5];
    const float* W          = (const float*)d_in[6];
    const float* gamma      = (const float*)d_in[7];
    const float* beta       = (const float*)d_in[8];
    const float* bn_mean    = (const float*)d_in[9];
    const float* bn_var     = (const float*)d_in[10];

    const int M = in_sizes[1] / CH;
    const int N = in_sizes[3] / CH;

    unsigned* Hvp  = (unsigned*)d_ws;                       // M * 128 B
    float4*   Vxyz = (float4*)((char*)d_ws + (size_t)M * 128);

    {
        dim3 grid((M + 63) / 64);
        voxel_mlp_mfma<<<grid, 256, 0, stream>>>(
            (const int4*)v_indices, (const float4*)v_features, (const float4*)W,
            gamma, beta, bn_mean, bn_var, Hvp, Vxyz, M);
    }
    {
        dim3 grid((N + 3) / 4);
        pool_kernel<<<grid, 256, 0, stream>>>(
            p_coords, p_features, p_map, p_mask,
            (const char*)Hvp, (const float4*)Vxyz, (float*)d_out, N);
    }
}

// Round 5
// 76.462 us; speedup vs baseline: 5.6227x; 1.0157x over previous
//
#include <hip/hip_runtime.h>

#define CH 64

typedef _Float16 half8  __attribute__((ext_vector_type(8)));
typedef _Float16 half2v __attribute__((ext_vector_type(2)));
typedef float    f32x4  __attribute__((ext_vector_type(4)));

__device__ __forceinline__ half8 cvt_half8(float4 a, float4 b) {
    half8 h;
    h[0] = (_Float16)a.x; h[1] = (_Float16)a.y; h[2] = (_Float16)a.z; h[3] = (_Float16)a.w;
    h[4] = (_Float16)b.x; h[5] = (_Float16)b.y; h[6] = (_Float16)b.z; h[7] = (_Float16)b.w;
    return h;
}

// ---------------------------------------------------------------------------
// Kernel 1: voxel MLP via MFMA fp16 (f32 accumulate). Unchanged (validated).
// Output row m: 32 dwords, dword j = (h[j], h[j+32]) fp16 pair.
// ---------------------------------------------------------------------------
__global__ __launch_bounds__(256) void voxel_mlp_mfma(
    const int4*   __restrict__ vi4,
    const float4* __restrict__ vf4,
    const float4* __restrict__ Wf4,
    const float*  __restrict__ gamma,
    const float*  __restrict__ beta,
    const float*  __restrict__ bn_mean,
    const float*  __restrict__ bn_var,
    unsigned*     __restrict__ Hvp,
    float4*       __restrict__ Vxyz,
    int M)
{
    const int t     = threadIdx.x;
    const int lane  = t & 63;
    const int wv    = t >> 6;
    const int row16 = lane & 15;
    const int kgrp  = lane >> 4;
    const int blockRow = blockIdx.x * 64;

    if (t < 64) {
        int r = blockRow + t;
        if (r < M) {
            int4 vi = vi4[r];
            float4 vx;
            vx.x = ((float)vi.w + 0.5f) * 0.1f;
            vx.y = ((float)vi.z + 0.5f) * 0.1f - 40.0f;
            vx.z = ((float)vi.y + 0.5f) * 0.2f - 3.0f;
            vx.w = 0.0f;
            Vxyz[r] = vx;
        }
    }

    half8 bfrag[4][2];
    #pragma unroll
    for (int ot = 0; ot < 4; ++ot) {
        int o = ot * 16 + row16;
        #pragma unroll
        for (int ck = 0; ck < 2; ++ck) {
            int c4 = ck * 8 + kgrp * 2;
            bfrag[ot][ck] = cvt_half8(Wf4[o * 16 + c4], Wf4[o * 16 + c4 + 1]);
        }
    }

    const int rbase = blockRow + wv * 16;
    int rc = rbase + row16; if (rc > M - 1) rc = M - 1;
    half8 afrag[2];
    #pragma unroll
    for (int ck = 0; ck < 2; ++ck) {
        int c4 = ck * 8 + kgrp * 2;
        afrag[ck] = cvt_half8(vf4[rc * 16 + c4], vf4[rc * 16 + c4 + 1]);
    }

    f32x4 acc[4] = {{0.f,0.f,0.f,0.f},{0.f,0.f,0.f,0.f},{0.f,0.f,0.f,0.f},{0.f,0.f,0.f,0.f}};
    #pragma unroll
    for (int ot = 0; ot < 4; ++ot) {
        acc[ot] = __builtin_amdgcn_mfma_f32_16x16x32_f16(afrag[0], bfrag[ot][0], acc[ot], 0, 0, 0);
        acc[ot] = __builtin_amdgcn_mfma_f32_16x16x32_f16(afrag[1], bfrag[ot][1], acc[ot], 0, 0, 0);
    }

    float sc[4], sh[4];
    #pragma unroll
    for (int ot = 0; ot < 4; ++ot) {
        int o = ot * 16 + row16;
        float s = gamma[o] * rsqrtf(bn_var[o] + 1e-5f);
        sc[ot] = s;
        sh[ot] = beta[o] - bn_mean[o] * s;
    }

    #pragma unroll
    for (int reg = 0; reg < 4; ++reg) {
        int row = rbase + kgrp * 4 + reg;
        if (row < M) {
            #pragma unroll
            for (int ot = 0; ot < 2; ++ot) {
                float v0 = fmaxf(fmaf(acc[ot][reg],     sc[ot],     sh[ot]),     0.f);
                float v1 = fmaxf(fmaf(acc[ot + 2][reg], sc[ot + 2], sh[ot + 2]), 0.f);
                half2v p; p[0] = (_Float16)v0; p[1] = (_Float16)v1;
                *reinterpret_cast<half2v*>(&Hvp[row * 32 + ot * 16 + row16]) = p;
            }
        }
    }
}

// ---------------------------------------------------------------------------
// Kernel 2: pooling. 2 points per wave, no LDS, no barrier.
// Lane roles per point:
//   gather: g = lane>>4 (sample group), k = lane&15 -> dwordx2 of 4 rows/instr
//   prepass: sp = lane>>2 (sample), j = lane&3 (geo component) -> wsel
//   weight broadcast to consumer lanes via ds_bpermute (__shfl, computed lane)
// ---------------------------------------------------------------------------
__device__ __forceinline__ void pool_point_compute(
    int n, int g, int k, int q0,
    float wsel, float mk, const uint2* h01,
    float2 pf, float* __restrict__ out, bool doStore)
{
    float den = mk;
    den += __shfl_xor(den, 4);
    den += __shfl_xor(den, 8);
    den += __shfl_xor(den, 16);
    den += __shfl_xor(den, 32);
    den = fmaxf(den, 1.0f);

    float acc0 = 0.f, acc1 = 0.f, acc2 = 0.f, acc3 = 0.f;
    #pragma unroll
    for (int i = 0; i < 4; ++i) {
        const int sl = (g << 4) + (i << 2) + q0;   // lane holding w[sample 4g+i][q0]
        float wlo = __shfl(wsel, sl);
        float whi = __shfl(wsel, sl + 1);
        half2v a = __builtin_bit_cast(half2v, h01[i].x);  // (h[2k],   h[2k+32])
        half2v b = __builtin_bit_cast(half2v, h01[i].y);  // (h[2k+1], h[2k+33])
        acc0 = fmaf((float)a[0], wlo, acc0);
        acc1 = fmaf((float)b[0], whi, acc1);
        acc2 = fmaf((float)a[1], wlo, acc2);
        acc3 = fmaf((float)b[1], whi, acc3);
    }
    acc0 += __shfl_xor(acc0, 16); acc0 += __shfl_xor(acc0, 32);
    acc1 += __shfl_xor(acc1, 16); acc1 += __shfl_xor(acc1, 32);
    acc2 += __shfl_xor(acc2, 16); acc2 += __shfl_xor(acc2, 32);
    acc3 += __shfl_xor(acc3, 16); acc3 += __shfl_xor(acc3, 32);

    if (doStore) {
        float r = 1.0f / den;
        float2 o;
        if (g == 0) { o.x = fmaf(acc0, r, pf.x); o.y = fmaf(acc1, r, pf.y); }
        else        { o.x = fmaf(acc2, r, pf.x); o.y = fmaf(acc3, r, pf.y); }
        *reinterpret_cast<float2*>(out + n * 64 + g * 32 + k * 2) = o;
    }
}

__global__ __launch_bounds__(256) void pool_kernel(
    const float*  __restrict__ p_coords,   // [N][4]
    const float*  __restrict__ p_features, // [N][64]
    const int*    __restrict__ p_map,      // [N][16]
    const float*  __restrict__ p_mask,     // [N][16]
    const char*   __restrict__ Hvp,        // [M*128 bytes]
    const float4* __restrict__ Vxyz,       // [M]
    float* __restrict__ out,               // [N][64]
    int N)
{
    const int lane = threadIdx.x & 63;
    const int wv   = threadIdx.x >> 6;
    int n0 = __builtin_amdgcn_readfirstlane(((int)blockIdx.x * 4 + wv) * 2);
    if (n0 >= N) return;
    int n1 = n0 + 1;
    const bool has1 = (n1 < N);
    if (!has1) n1 = n0;

    const int g  = lane >> 4;
    const int k  = lane & 15;
    const int q0 = (lane & 1) * 2;
    const int sp = lane >> 2;
    const int j  = lane & 3;

    // ---------------- load phase: both points ----------------
    const int4 m4a = ((const int4*)(p_map + n0 * 16))[g];
    const int4 m4b = ((const int4*)(p_map + n1 * 16))[g];
    const unsigned co = (unsigned)k * 8u;

    uint2 ha[4], hb[4];
    ha[0] = *(const uint2*)(Hvp + ((unsigned)m4a.x * 128u + co));
    ha[1] = *(const uint2*)(Hvp + ((unsigned)m4a.y * 128u + co));
    ha[2] = *(const uint2*)(Hvp + ((unsigned)m4a.z * 128u + co));
    ha[3] = *(const uint2*)(Hvp + ((unsigned)m4a.w * 128u + co));
    hb[0] = *(const uint2*)(Hvp + ((unsigned)m4b.x * 128u + co));
    hb[1] = *(const uint2*)(Hvp + ((unsigned)m4b.y * 128u + co));
    hb[2] = *(const uint2*)(Hvp + ((unsigned)m4b.z * 128u + co));
    hb[3] = *(const uint2*)(Hvp + ((unsigned)m4b.w * 128u + co));

    const int   mia = p_map [n0 * 16 + sp];
    const int   mib = p_map [n1 * 16 + sp];
    const float mka = p_mask[n0 * 16 + sp];
    const float mkb = p_mask[n1 * 16 + sp];
    const float4 va = Vxyz[mia];
    const float4 vb = Vxyz[mib];

    float2 pfa = make_float2(0.f, 0.f), pfb = make_float2(0.f, 0.f);
    if (g < 2) {
        pfa = *(const float2*)(p_features + n0 * 64 + g * 32 + k * 2);
        pfb = *(const float2*)(p_features + n1 * 64 + g * 32 + k * 2);
    }

    // ---------------- point A ----------------
    {
        const float cx = p_coords[n0 * 4 + 1];
        const float cy = p_coords[n0 * 4 + 2];
        const float cz = p_coords[n0 * 4 + 3];
        float rx = va.x - cx, ry = va.y - cy, rz = va.z - cz;
        float d  = fmaf(rx, rx, fmaf(ry, ry, rz * rz));
        float lo = (j & 1) ? ry * 10.0f : rx * 10.0f;
        float hi = (j & 1) ? d * (1.0f / 0.06f) : rz * 5.0f;
        float wsel = ((j & 2) ? hi : lo) * mka;
        pool_point_compute(n0, g, k, q0, wsel, mka, ha, pfa, out, g < 2);
    }
    // ---------------- point B ----------------
    {
        const float cx = p_coords[n1 * 4 + 1];
        const float cy = p_coords[n1 * 4 + 2];
        const float cz = p_coords[n1 * 4 + 3];
        float rx = vb.x - cx, ry = vb.y - cy, rz = vb.z - cz;
        float d  = fmaf(rx, rx, fmaf(ry, ry, rz * rz));
        float lo = (j & 1) ? ry * 10.0f : rx * 10.0f;
        float hi = (j & 1) ? d * (1.0f / 0.06f) : rz * 5.0f;
        float wsel = ((j & 2) ? hi : lo) * mkb;
        pool_point_compute(n1, g, k, q0, wsel, mkb, hb, pfb, out, (g < 2) && has1);
    }
}

extern "C" void kernel_launch(void* const* d_in, const int* in_sizes, int n_in,
                              void* d_out, int out_size, void* d_ws, size_t ws_size,
                              hipStream_t stream) {
    const int*   v_indices  = (const int*)  d_in[0];
    const float* v_features = (const float*)d_in[1];
    const float* p_coords   = (const float*)d_in[2];
    const float* p_features = (const float*)d_in[3];
    const int*   p_map      = (const int*)  d_in[4];
    const float* p_mask     = (const float*)d_in[5];
    const float* W          = (const float*)d_in[6];
    const float* gamma      = (const float*)d_in[7];
    const float* beta       = (const float*)d_in[8];
    const float* bn_mean    = (const float*)d_in[9];
    const float* bn_var     = (const float*)d_in[10];

    const int M = in_sizes[1] / CH;
    const int N = in_sizes[3] / CH;

    unsigned* Hvp  = (unsigned*)d_ws;                       // M * 128 B
    float4*   Vxyz = (float4*)((char*)d_ws + (size_t)M * 128);

    {
        dim3 grid((M + 63) / 64);
        voxel_mlp_mfma<<<grid, 256, 0, stream>>>(
            (const int4*)v_indices, (const float4*)v_features, (const float4*)W,
            gamma, beta, bn_mean, bn_var, Hvp, Vxyz, M);
    }
    {
        dim3 grid((N + 7) / 8);   // 4 waves/block, 2 points/wave
        pool_kernel<<<grid, 256, 0, stream>>>(
            p_coords, p_features, p_map, p_mask,
            (const char*)Hvp, (const float4*)Vxyz, (float*)d_out, N);
    }
}

// Round 7
// 64.624 us; speedup vs baseline: 6.6526x; 1.1832x over previous
//
#include <hip/hip_runtime.h>

#define CH 64

typedef _Float16 half8  __attribute__((ext_vector_type(8)));
typedef _Float16 half2v __attribute__((ext_vector_type(2)));
typedef __fp16   fp16x2 __attribute__((ext_vector_type(2)));
typedef float    f32x4  __attribute__((ext_vector_type(4)));

// pack 2 f32 -> half2 (RTZ, single VALU op)
__device__ __forceinline__ half2v pk(float a, float b) {
    fp16x2 r = __builtin_amdgcn_cvt_pkrtz(a, b);
    return __builtin_bit_cast(half2v, r);
}

// ---------------------------------------------------------------------------
// Kernel 0: prepack W (f32 [64][64]) into fp16 MFMA B-fragments.
// Output Whp8[t], t = (ck*4+kgrp)*64 + o : half8 = W[o][32ck+8kgrp .. +7].
// 512 threads total.
// ---------------------------------------------------------------------------
__global__ __launch_bounds__(512) void prepack_w(
    const float4* __restrict__ Wf4,   // [64*16]
    half8* __restrict__ Whp8)         // [512]
{
    const int t = threadIdx.x;        // 0..511
    const int o    = t & 63;
    const int grp  = t >> 6;          // 0..7
    const int kgrp = grp & 3;
    const int ck   = grp >> 2;
    const int c4   = ck * 8 + kgrp * 2;       // float4 index
    float4 a = Wf4[o * 16 + c4];
    float4 b = Wf4[o * 16 + c4 + 1];
    half8 h;
    half2v p0 = pk(a.x, a.y), p1 = pk(a.z, a.w);
    half2v p2 = pk(b.x, b.y), p3 = pk(b.z, b.w);
    h[0]=p0[0]; h[1]=p0[1]; h[2]=p1[0]; h[3]=p1[1];
    h[4]=p2[0]; h[5]=p2[1]; h[6]=p3[0]; h[7]=p3[1];
    Whp8[t] = h;
}

// ---------------------------------------------------------------------------
// Kernel 1: voxel MLP via MFMA fp16 (f32 accumulate), prepacked W.
// Output row m: 32 dwords, dword j = (h[j], h[j+32]) fp16 pair.
// ---------------------------------------------------------------------------
__global__ __launch_bounds__(256) void voxel_mlp_mfma(
    const int4*   __restrict__ vi4,
    const float4* __restrict__ vf4,
    const half8*  __restrict__ Whp8,
    const float*  __restrict__ gamma,
    const float*  __restrict__ beta,
    const float*  __restrict__ bn_mean,
    const float*  __restrict__ bn_var,
    unsigned*     __restrict__ Hvp,
    float4*       __restrict__ Vxyz,
    int M)
{
    const int t     = threadIdx.x;
    const int lane  = t & 63;
    const int wv    = t >> 6;
    const int row16 = lane & 15;
    const int kgrp  = lane >> 4;
    const int blockRow = blockIdx.x * 64;

    if (t < 64) {
        int r = blockRow + t;
        if (r < M) {
            int4 vi = vi4[r];
            float4 vx;
            vx.x = ((float)vi.w + 0.5f) * 0.1f;
            vx.y = ((float)vi.z + 0.5f) * 0.1f - 40.0f;
            vx.z = ((float)vi.y + 0.5f) * 0.2f - 3.0f;
            vx.w = 0.0f;
            Vxyz[r] = vx;
        }
    }

    // B fragments: straight 16B loads, no conversion
    half8 bfrag[4][2];
    #pragma unroll
    for (int ck = 0; ck < 2; ++ck) {
        #pragma unroll
        for (int ot = 0; ot < 4; ++ot)
            bfrag[ot][ck] = Whp8[(ck * 4 + kgrp) * 64 + ot * 16 + row16];
    }

    // A fragments: v_features rows (f32 -> fp16 via pkrtz)
    const int rbase = blockRow + wv * 16;
    int rc = rbase + row16; if (rc > M - 1) rc = M - 1;
    half8 afrag[2];
    #pragma unroll
    for (int ck = 0; ck < 2; ++ck) {
        int c4 = ck * 8 + kgrp * 2;
        float4 a = vf4[rc * 16 + c4];
        float4 b = vf4[rc * 16 + c4 + 1];
        half8 h;
        half2v p0 = pk(a.x, a.y), p1 = pk(a.z, a.w);
        half2v p2 = pk(b.x, b.y), p3 = pk(b.z, b.w);
        h[0]=p0[0]; h[1]=p0[1]; h[2]=p1[0]; h[3]=p1[1];
        h[4]=p2[0]; h[5]=p2[1]; h[6]=p3[0]; h[7]=p3[1];
        afrag[ck] = h;
    }

    f32x4 acc[4] = {{0.f,0.f,0.f,0.f},{0.f,0.f,0.f,0.f},{0.f,0.f,0.f,0.f},{0.f,0.f,0.f,0.f}};
    #pragma unroll
    for (int ot = 0; ot < 4; ++ot) {
        acc[ot] = __builtin_amdgcn_mfma_f32_16x16x32_f16(afrag[0], bfrag[ot][0], acc[ot], 0, 0, 0);
        acc[ot] = __builtin_amdgcn_mfma_f32_16x16x32_f16(afrag[1], bfrag[ot][1], acc[ot], 0, 0, 0);
    }

    float sc[4], sh[4];
    #pragma unroll
    for (int ot = 0; ot < 4; ++ot) {
        int o = ot * 16 + row16;
        float s = gamma[o] * rsqrtf(bn_var[o] + 1e-5f);
        sc[ot] = s;
        sh[ot] = beta[o] - bn_mean[o] * s;
    }

    #pragma unroll
    for (int reg = 0; reg < 4; ++reg) {
        int row = rbase + kgrp * 4 + reg;
        if (row < M) {
            #pragma unroll
            for (int ot = 0; ot < 2; ++ot) {
                float v0 = fmaxf(fmaf(acc[ot][reg],     sc[ot],     sh[ot]),     0.f);
                float v1 = fmaxf(fmaf(acc[ot + 2][reg], sc[ot + 2], sh[ot + 2]), 0.f);
                half2v p = pk(v0, v1);
                *reinterpret_cast<half2v*>(&Hvp[row * 32 + ot * 16 + row16]) = p;
            }
        }
    }
}

// ---------------------------------------------------------------------------
// Kernel 2: pooling. 2 points per wave, no LDS, no barrier.
// Gathers predicated on mask!=0 (exec-masked -> masked rows' lines never
// requested; 25% of samples are masked out).
// ---------------------------------------------------------------------------
__device__ __forceinline__ void pool_point_compute(
    int n, int g, int k, int q0,
    float wsel, float mk, const uint2* h01,
    float2 pf, float* __restrict__ out, bool doStore)
{
    float den = mk;
    den += __shfl_xor(den, 4);
    den += __shfl_xor(den, 8);
    den += __shfl_xor(den, 16);
    den += __shfl_xor(den, 32);
    den = fmaxf(den, 1.0f);

    float acc0 = 0.f, acc1 = 0.f, acc2 = 0.f, acc3 = 0.f;
    #pragma unroll
    for (int i = 0; i < 4; ++i) {
        const int sl = (g << 4) + (i << 2) + q0;
        float wlo = __shfl(wsel, sl);
        float whi = __shfl(wsel, sl + 1);
        half2v a = __builtin_bit_cast(half2v, h01[i].x);
        half2v b = __builtin_bit_cast(half2v, h01[i].y);
        acc0 = fmaf((float)a[0], wlo, acc0);
        acc1 = fmaf((float)b[0], whi, acc1);
        acc2 = fmaf((float)a[1], wlo, acc2);
        acc3 = fmaf((float)b[1], whi, acc3);
    }
    acc0 += __shfl_xor(acc0, 16); acc0 += __shfl_xor(acc0, 32);
    acc1 += __shfl_xor(acc1, 16); acc1 += __shfl_xor(acc1, 32);
    acc2 += __shfl_xor(acc2, 16); acc2 += __shfl_xor(acc2, 32);
    acc3 += __shfl_xor(acc3, 16); acc3 += __shfl_xor(acc3, 32);

    if (doStore) {
        float r = 1.0f / den;
        float2 o;
        if (g == 0) { o.x = fmaf(acc0, r, pf.x); o.y = fmaf(acc1, r, pf.y); }
        else        { o.x = fmaf(acc2, r, pf.x); o.y = fmaf(acc3, r, pf.y); }
        *reinterpret_cast<float2*>(out + n * 64 + g * 32 + k * 2) = o;
    }
}

__global__ __launch_bounds__(256) void pool_kernel(
    const float*  __restrict__ p_coords,   // [N][4]
    const float*  __restrict__ p_features, // [N][64]
    const int*    __restrict__ p_map,      // [N][16]
    const float*  __restrict__ p_mask,     // [N][16]
    const char*   __restrict__ Hvp,        // [M*128 bytes]
    const float4* __restrict__ Vxyz,       // [M]
    float* __restrict__ out,               // [N][64]
    int N)
{
    const int lane = threadIdx.x & 63;
    const int wv   = threadIdx.x >> 6;
    int n0 = __builtin_amdgcn_readfirstlane(((int)blockIdx.x * 4 + wv) * 2);
    if (n0 >= N) return;
    int n1 = n0 + 1;
    const bool has1 = (n1 < N);
    if (!has1) n1 = n0;

    const int g  = lane >> 4;
    const int k  = lane & 15;
    const int q0 = (lane & 1) * 2;
    const int sp = lane >> 2;
    const int j  = lane & 3;

    // ---------------- load phase: both points ----------------
    const int4   m4a  = ((const int4*)  (p_map  + n0 * 16))[g];
    const int4   m4b  = ((const int4*)  (p_map  + n1 * 16))[g];
    const float4 mk4a = ((const float4*)(p_mask + n0 * 16))[g];
    const float4 mk4b = ((const float4*)(p_mask + n1 * 16))[g];
    const unsigned co = (unsigned)k * 8u;

    uint2 ha[4], hb[4];
    #pragma unroll
    for (int i = 0; i < 4; ++i) { ha[i] = make_uint2(0u,0u); hb[i] = make_uint2(0u,0u); }
    if (mk4a.x != 0.f) ha[0] = *(const uint2*)(Hvp + ((unsigned)m4a.x * 128u + co));
    if (mk4a.y != 0.f) ha[1] = *(const uint2*)(Hvp + ((unsigned)m4a.y * 128u + co));
    if (mk4a.z != 0.f) ha[2] = *(const uint2*)(Hvp + ((unsigned)m4a.z * 128u + co));
    if (mk4a.w != 0.f) ha[3] = *(const uint2*)(Hvp + ((unsigned)m4a.w * 128u + co));
    if (mk4b.x != 0.f) hb[0] = *(const uint2*)(Hvp + ((unsigned)m4b.x * 128u + co));
    if (mk4b.y != 0.f) hb[1] = *(const uint2*)(Hvp + ((unsigned)m4b.y * 128u + co));
    if (mk4b.z != 0.f) hb[2] = *(const uint2*)(Hvp + ((unsigned)m4b.z * 128u + co));
    if (mk4b.w != 0.f) hb[3] = *(const uint2*)(Hvp + ((unsigned)m4b.w * 128u + co));

    const int   mia = p_map [n0 * 16 + sp];
    const int   mib = p_map [n1 * 16 + sp];
    const float mka = p_mask[n0 * 16 + sp];
    const float mkb = p_mask[n1 * 16 + sp];
    const float4 va = Vxyz[mia];
    const float4 vb = Vxyz[mib];

    float2 pfa = make_float2(0.f, 0.f), pfb = make_float2(0.f, 0.f);
    if (g < 2) {
        pfa = *(const float2*)(p_features + n0 * 64 + g * 32 + k * 2);
        pfb = *(const float2*)(p_features + n1 * 64 + g * 32 + k * 2);
    }

    // ---------------- point A ----------------
    {
        const float cx = p_coords[n0 * 4 + 1];
        const float cy = p_coords[n0 * 4 + 2];
        const float cz = p_coords[n0 * 4 + 3];
        float rx = va.x - cx, ry = va.y - cy, rz = va.z - cz;
        float d  = fmaf(rx, rx, fmaf(ry, ry, rz * rz));
        float lo = (j & 1) ? ry * 10.0f : rx * 10.0f;
        float hi = (j & 1) ? d * (1.0f / 0.06f) : rz * 5.0f;
        float wsel = ((j & 2) ? hi : lo) * mka;
        pool_point_compute(n0, g, k, q0, wsel, mka, ha, pfa, out, g < 2);
    }
    // ---------------- point B ----------------
    {
        const float cx = p_coords[n1 * 4 + 1];
        const float cy = p_coords[n1 * 4 + 2];
        const float cz = p_coords[n1 * 4 + 3];
        float rx = vb.x - cx, ry = vb.y - cy, rz = vb.z - cz;
        float d  = fmaf(rx, rx, fmaf(ry, ry, rz * rz));
        float lo = (j & 1) ? ry * 10.0f : rx * 10.0f;
        float hi = (j & 1) ? d * (1.0f / 0.06f) : rz * 5.0f;
        float wsel = ((j & 2) ? hi : lo) * mkb;
        pool_point_compute(n1, g, k, q0, wsel, mkb, hb, pfb, out, (g < 2) && has1);
    }
}

extern "C" void kernel_launch(void* const* d_in, const int* in_sizes, int n_in,
                              void* d_out, int out_size, void* d_ws, size_t ws_size,
                              hipStream_t stream) {
    const int*   v_indices  = (const int*)  d_in[0];
    const float* v_features = (const float*)d_in[1];
    const float* p_coords   = (const float*)d_in[2];
    const float* p_features = (const float*)d_in[3];
    const int*   p_map      = (const int*)  d_in[4];
    const float* p_mask     = (const float*)d_in[5];
    const float* W          = (const float*)d_in[6];
    const float* gamma      = (const float*)d_in[7];
    const float* beta       = (const float*)d_in[8];
    const float* bn_mean    = (const float*)d_in[9];
    const float* bn_var     = (const float*)d_in[10];

    const int M = in_sizes[1] / CH;
    const int N = in_sizes[3] / CH;

    unsigned* Hvp  = (unsigned*)d_ws;                                   // M*128 B
    float4*   Vxyz = (float4*)((char*)d_ws + (size_t)M * 128);          // M*16 B
    half8*    Whp8 = (half8*)((char*)d_ws + (size_t)M * 144);           // 8 KB

    prepack_w<<<1, 512, 0, stream>>>((const float4*)W, Whp8);
    {
        dim3 grid((M + 63) / 64);
        voxel_mlp_mfma<<<grid, 256, 0, stream>>>(
            (const int4*)v_indices, (const float4*)v_features, Whp8,
            gamma, beta, bn_mean, bn_var, Hvp, Vxyz, M);
    }
    {
        dim3 grid((N + 7) / 8);   // 4 waves/block, 2 points/wave
        pool_kernel<<<grid, 256, 0, stream>>>(
            p_coords, p_features, p_map, p_mask,
            (const char*)Hvp, (const float4*)Vxyz, (float*)d_out, N);
    }
}